// Round 1
// baseline (2965.307 us; speedup 1.0000x reference)
//
#include <hip/hip_runtime.h>

#define NN 50000
#define EE 100000
#define LL 2

#define XT_S 20      // XT row stride (floats): [64][20], float4-aligned
#define Q_S  80      // Q row stride in A region: [16][80]
#define WAVE_LDS 3328  // A(1280) + K(1024) + V(1024)

// ---------------- small prep kernels ----------------

__global__ __launch_bounds__(256)
void count_kernel(const int* __restrict__ tgt, float* __restrict__ rcnt) {
    int e = blockIdx.x * 256 + threadIdx.x;
    if (e < EE) atomicAdd(&rcnt[tgt[e]], 1.0f);
}

__global__ __launch_bounds__(256)
void recip_kernel(float* __restrict__ rcnt) {
    int n = blockIdx.x * 256 + threadIdx.x;
    if (n < NN) rcnt[n] = 1.0f / fmaxf(rcnt[n], 1.0f);
}

__global__ __launch_bounds__(256)
void embed_kernel(const float* __restrict__ x, const float* __restrict__ nw,
                  const float* __restrict__ nb, float* __restrict__ h0) {
    int gid = blockIdx.x * 256 + threadIdx.x;
    if (gid >= NN * 512) return;
    int n = gid >> 9, j = gid & 511;
    h0[gid] = x[n * 8 + (j >> 6)] * nw[j] + nb[j];
}

// Transpose all weight matrices so the per-edge kernel reads them coalesced:
// layout per layer (28672 floats): bprojT[k*64+d] | ipwT[k*192+j] | opwT[k*64+d] | ff1T[k*64+f] | ff2T[f*64+d]
__global__ __launch_bounds__(256)
void prep_weights_kernel(const float* __restrict__ bproj_w,
                         const float* __restrict__ in_proj_w,
                         const float* __restrict__ out_proj_w,
                         const float* __restrict__ ff1_w,
                         const float* __restrict__ ff2_w,
                         float* __restrict__ wt) {
    int r = blockIdx.x * 256 + threadIdx.x;
    if (r >= LL * 28672) return;
    int l = r / 28672;
    int u = r % 28672;
    float v;
    if (u < 4096) {
        int k = u >> 6, d = u & 63;
        v = bproj_w[l * 4096 + d * 64 + k];
    } else if (u < 16384) {
        int w = u - 4096; int k = w / 192, j = w % 192;
        v = in_proj_w[l * 12288 + j * 64 + k];
    } else if (u < 20480) {
        int w = u - 16384; int k = w >> 6, d = w & 63;
        v = out_proj_w[l * 4096 + d * 64 + k];
    } else if (u < 24576) {
        int w = u - 20480; int k = w >> 6, f = w & 63;
        v = ff1_w[l * 4096 + f * 64 + k];
    } else {
        int w = u - 24576; int f = w >> 6, d = w & 63;
        v = ff2_w[l * 4096 + d * 64 + f];
    }
    wt[r] = v;
}

// ---------------- fused per-edge layer kernel ----------------

__device__ __forceinline__ void load_row16(const float* A, int k, float* s) {
    const float4* row = (const float4*)(A + k * XT_S);
    float4 a = row[0], b = row[1], c = row[2], d = row[3];
    s[0]=a.x; s[1]=a.y; s[2]=a.z; s[3]=a.w;
    s[4]=b.x; s[5]=b.y; s[6]=b.z; s[7]=b.w;
    s[8]=c.x; s[9]=c.y; s[10]=c.z; s[11]=c.w;
    s[12]=d.x; s[13]=d.y; s[14]=d.z; s[15]=d.w;
}

__global__ __launch_bounds__(256)
void layer_kernel(const float* __restrict__ h_in, float* __restrict__ h_out,
                  const int* __restrict__ src, const int* __restrict__ tgt,
                  const float* __restrict__ rcnt, const float* __restrict__ wt,
                  const float* __restrict__ bpb, const float* __restrict__ ipb,
                  const float* __restrict__ opb,
                  const float* __restrict__ g1v, const float* __restrict__ b1v,
                  const float* __restrict__ g2v, const float* __restrict__ b2v,
                  const float* __restrict__ f1b, const float* __restrict__ f2b)
{
    __shared__ __align__(16) float lds[4 * WAVE_LDS];
    const int wv = threadIdx.x >> 6;
    const int lane = threadIdx.x & 63;
    const int e = blockIdx.x * 4 + wv;
    if (e >= EE) return;

    float* A  = lds + wv * WAVE_LDS;  // XT [64][20] -> Q [16][80] -> oT [64][20] -> xT/fT
    float* Kb = A + 1280;             // K [16][64]
    float* Vb = Kb + 1024;            // V [16][64]

    const float* bprojT = wt;
    const float* ipwT   = wt + 4096;
    const float* opwT   = wt + 16384;
    const float* ff1T   = wt + 20480;
    const float* ff2T   = wt + 24576;

    const int sn = src[e], tn = tgt[e];
    const float* hsrc = h_in + (size_t)sn * 512;
    const float* htgt = h_in + (size_t)tn * 512;

    float xc[16];
#pragma unroll
    for (int t = 0; t < 8; t++) xc[t] = htgt[t * 64 + lane];
    // stage x_src^T for bproj
#pragma unroll
    for (int t = 0; t < 8; t++) A[lane * XT_S + t] = hsrc[t * 64 + lane];

    // ---- bproj: xc[8..15] = x_src @ bproj_w^T + bpb ----
    {
        float acc[8] = {0,0,0,0,0,0,0,0};
#pragma unroll 4
        for (int k = 0; k < 64; k++) {
            float w = bprojT[k * 64 + lane];
            const float4* row = (const float4*)(A + k * XT_S);
            float4 a = row[0], b = row[1];
            acc[0]+=a.x*w; acc[1]+=a.y*w; acc[2]+=a.z*w; acc[3]+=a.w*w;
            acc[4]+=b.x*w; acc[5]+=b.y*w; acc[6]+=b.z*w; acc[7]+=b.w*w;
        }
        float bb = bpb[lane];
#pragma unroll
        for (int t = 0; t < 8; t++) xc[8 + t] = acc[t] + bb;
    }

    // ---- stage xc^T, in_proj -> q,k,v ----
#pragma unroll
    for (int t = 0; t < 16; t++) A[lane * XT_S + t] = xc[t];

    float q[16], kreg[16], vreg[16];
#pragma unroll
    for (int t = 0; t < 16; t++) { q[t] = 0; kreg[t] = 0; vreg[t] = 0; }
#pragma unroll 2
    for (int k = 0; k < 64; k++) {
        float w0 = ipwT[k * 192 + lane];
        float w1 = ipwT[k * 192 + 64 + lane];
        float w2 = ipwT[k * 192 + 128 + lane];
        float s[16]; load_row16(A, k, s);
#pragma unroll
        for (int t = 0; t < 16; t++) { q[t] += s[t]*w0; kreg[t] += s[t]*w1; vreg[t] += s[t]*w2; }
    }
    {
        float bq = ipb[lane], bk = ipb[64 + lane], bv = ipb[128 + lane];
#pragma unroll
        for (int t = 0; t < 16; t++) { q[t] += bq; kreg[t] += bk; vreg[t] += bv; }
    }
#pragma unroll
    for (int t = 0; t < 16; t++) { Kb[t * 64 + lane] = kreg[t]; Vb[t * 64 + lane] = vreg[t]; }
    // Q overwrites the (now dead) XT region
#pragma unroll
    for (int t = 0; t < 16; t++) A[t * Q_S + lane] = q[t];

    // ---- attention: lane = (head hh, query token qt) ----
    const int hh = lane >> 4, qt = lane & 15;
    float qf[16];
    {
        const float4* qr = (const float4*)(A + qt * Q_S + hh * 16);
        float4 a = qr[0], b = qr[1], c = qr[2], d = qr[3];
        qf[0]=a.x; qf[1]=a.y; qf[2]=a.z; qf[3]=a.w;
        qf[4]=b.x; qf[5]=b.y; qf[6]=b.z; qf[7]=b.w;
        qf[8]=c.x; qf[9]=c.y; qf[10]=c.z; qf[11]=c.w;
        qf[12]=d.x; qf[13]=d.y; qf[14]=d.z; qf[15]=d.w;
    }
    float sc[16];
#pragma unroll
    for (int kt = 0; kt < 16; kt++) {
        const float4* kr = (const float4*)(Kb + kt * 64 + hh * 16);
        float4 a = kr[0], b = kr[1], c = kr[2], d = kr[3];
        float s = qf[0]*a.x + qf[1]*a.y + qf[2]*a.z + qf[3]*a.w
                + qf[4]*b.x + qf[5]*b.y + qf[6]*b.z + qf[7]*b.w
                + qf[8]*c.x + qf[9]*c.y + qf[10]*c.z + qf[11]*c.w
                + qf[12]*d.x + qf[13]*d.y + qf[14]*d.z + qf[15]*d.w;
        sc[kt] = s * 0.25f;  // 1/sqrt(HD=16)
    }
    float mx = sc[0];
#pragma unroll
    for (int kt = 1; kt < 16; kt++) mx = fmaxf(mx, sc[kt]);
    float den = 0;
#pragma unroll
    for (int kt = 0; kt < 16; kt++) { sc[kt] = __expf(sc[kt] - mx); den += sc[kt]; }
    float inv = 1.0f / den;
    float of[16];
#pragma unroll
    for (int j = 0; j < 16; j++) of[j] = 0;
#pragma unroll
    for (int kt = 0; kt < 16; kt++) {
        const float4* vr = (const float4*)(Vb + kt * 64 + hh * 16);
        float4 a = vr[0], b = vr[1], c = vr[2], d = vr[3];
        float p = sc[kt] * inv;
        of[0]+=p*a.x; of[1]+=p*a.y; of[2]+=p*a.z; of[3]+=p*a.w;
        of[4]+=p*b.x; of[5]+=p*b.y; of[6]+=p*b.z; of[7]+=p*b.w;
        of[8]+=p*c.x; of[9]+=p*c.y; of[10]+=p*c.z; of[11]+=p*c.w;
        of[12]+=p*d.x; of[13]+=p*d.y; of[14]+=p*d.z; of[15]+=p*d.w;
    }
    // write o^T into A (Q is dead)
#pragma unroll
    for (int j = 0; j < 16; j++) A[(hh * 16 + j) * XT_S + qt] = of[j];

    // ---- out_proj + residual + LN1 ----
    {
        float acc[16];
#pragma unroll
        for (int t = 0; t < 16; t++) acc[t] = 0;
#pragma unroll 4
        for (int k = 0; k < 64; k++) {
            float w = opwT[k * 64 + lane];
            float s[16]; load_row16(A, k, s);
#pragma unroll
            for (int t = 0; t < 16; t++) acc[t] += s[t] * w;
        }
        float bo = opb[lane];
#pragma unroll
        for (int t = 0; t < 16; t++) xc[t] += acc[t] + bo;
    }
    {
        float gg = g1v[lane], bb = b1v[lane];
#pragma unroll
        for (int t = 0; t < 16; t++) {
            float a = xc[t];
            float s1 = a, s2 = a * a;
#pragma unroll
            for (int m = 1; m < 64; m <<= 1) { s1 += __shfl_xor(s1, m); s2 += __shfl_xor(s2, m); }
            float mean = s1 * 0.015625f;
            float var = s2 * 0.015625f - mean * mean;
            xc[t] = (a - mean) * rsqrtf(var + 1e-5f) * gg + bb;
        }
    }

    // ---- FF (64 -> 64 relu -> 64) + residual + LN2 ----
#pragma unroll
    for (int t = 0; t < 16; t++) A[lane * XT_S + t] = xc[t];
    {
        float f[16];
#pragma unroll
        for (int t = 0; t < 16; t++) f[t] = 0;
#pragma unroll 4
        for (int k = 0; k < 64; k++) {
            float w = ff1T[k * 64 + lane];
            float s[16]; load_row16(A, k, s);
#pragma unroll
            for (int t = 0; t < 16; t++) f[t] += s[t] * w;
        }
        float bf = f1b[lane];
#pragma unroll
        for (int t = 0; t < 16; t++) f[t] = fmaxf(f[t] + bf, 0.0f);
#pragma unroll
        for (int t = 0; t < 16; t++) A[lane * XT_S + t] = f[t];
    }
    {
        float g_[16];
#pragma unroll
        for (int t = 0; t < 16; t++) g_[t] = 0;
#pragma unroll 4
        for (int k = 0; k < 64; k++) {
            float w = ff2T[k * 64 + lane];
            float s[16]; load_row16(A, k, s);
#pragma unroll
            for (int t = 0; t < 16; t++) g_[t] += s[t] * w;
        }
        float bf = f2b[lane];
#pragma unroll
        for (int t = 0; t < 16; t++) xc[t] += g_[t] + bf;
    }
    {
        float gg = g2v[lane], bb = b2v[lane];
#pragma unroll
        for (int t = 0; t < 16; t++) {
            float a = xc[t];
            float s1 = a, s2 = a * a;
#pragma unroll
            for (int m = 1; m < 64; m <<= 1) { s1 += __shfl_xor(s1, m); s2 += __shfl_xor(s2, m); }
            float mean = s1 * 0.015625f;
            float var = s2 * 0.015625f - mean * mean;
            xc[t] = (a - mean) * rsqrtf(var + 1e-5f) * gg + bb;
        }
    }

    // ---- scatter first 8 tokens with mean scaling ----
    float rc = rcnt[tn];
#pragma unroll
    for (int t = 0; t < 8; t++)
        atomicAdd(&h_out[(size_t)tn * 512 + t * 64 + lane], xc[t] * rc);
}

// ---------------- final projection + softmax ----------------

__global__ __launch_bounds__(256)
void out_kernel(const float* __restrict__ h, const float* __restrict__ ow,
                const float* __restrict__ ob, float* __restrict__ out)
{
    __shared__ __align__(16) float hl[16 * 516];
    __shared__ __align__(16) float wl[16 * 68];
    __shared__ float bl[16];
    const int tid = threadIdx.x;
    const int n0 = blockIdx.x * 16;
#pragma unroll
    for (int i = 0; i < 4; i++) {
        int idx = i * 256 + tid;
        wl[(idx >> 6) * 68 + (idx & 63)] = ow[idx];
    }
    if (tid < 16) bl[tid] = ob[tid];
#pragma unroll
    for (int i = 0; i < 32; i++) {
        int idx = i * 256 + tid; int nl = idx >> 9, j = idx & 511;
        hl[nl * 516 + j] = h[(size_t)(n0 + nl) * 512 + j];
    }
    __syncthreads();
    const int nl = tid >> 4, o = tid & 15;
    float acc = 0;
#pragma unroll 4
    for (int d4 = 0; d4 < 16; d4++) {
        float4 wv = *(const float4*)&wl[o * 68 + d4 * 4];
#pragma unroll
        for (int c = 0; c < 8; c++) {
            float4 hv = *(const float4*)&hl[nl * 516 + c * 64 + d4 * 4];
            acc += hv.x*wv.x + hv.y*wv.y + hv.z*wv.z + hv.w*wv.w;
        }
    }
    float z = acc + 8.0f * bl[o];
    float mxv = z;
#pragma unroll
    for (int m = 1; m < 16; m <<= 1) mxv = fmaxf(mxv, __shfl_xor(mxv, m));
    float ez = __expf(z - mxv);
    float sm = ez;
#pragma unroll
    for (int m = 1; m < 16; m <<= 1) sm += __shfl_xor(sm, m);
    out[(size_t)(n0 + nl) * 16 + o] = ez / sm;
}

// ---------------- launch ----------------

extern "C" void kernel_launch(void* const* d_in, const int* in_sizes, int n_in,
                              void* d_out, int out_size, void* d_ws, size_t ws_size,
                              hipStream_t stream)
{
    const float* x   = (const float*)d_in[0];
    const int*   ei  = (const int*)d_in[1];
    const float* nw  = (const float*)d_in[2];
    const float* nb  = (const float*)d_in[3];
    const float* bpw = (const float*)d_in[4];
    const float* bpb = (const float*)d_in[5];
    const float* ipw = (const float*)d_in[6];
    const float* ipb = (const float*)d_in[7];
    const float* opw = (const float*)d_in[8];
    const float* opb = (const float*)d_in[9];
    const float* g1  = (const float*)d_in[10];
    const float* b1  = (const float*)d_in[11];
    const float* g2  = (const float*)d_in[12];
    const float* b2  = (const float*)d_in[13];
    const float* f1w = (const float*)d_in[14];
    const float* f1b = (const float*)d_in[15];
    const float* f2w = (const float*)d_in[16];
    const float* f2b = (const float*)d_in[17];
    const float* ow  = (const float*)d_in[18];
    const float* ob  = (const float*)d_in[19];

    float* ws   = (float*)d_ws;
    float* h0   = ws;
    float* h1   = h0 + (size_t)NN * 512;
    float* rcnt = h1 + (size_t)NN * 512;
    float* wt   = rcnt + NN;

    hipMemsetAsync(rcnt, 0, NN * sizeof(float), stream);
    count_kernel<<<(EE + 255) / 256, 256, 0, stream>>>(ei + EE, rcnt);
    recip_kernel<<<(NN + 255) / 256, 256, 0, stream>>>(rcnt);
    prep_weights_kernel<<<(LL * 28672 + 255) / 256, 256, 0, stream>>>(bpw, ipw, opw, f1w, f2w, wt);
    embed_kernel<<<(NN * 512) / 256, 256, 0, stream>>>(x, nw, nb, h0);

    hipMemsetAsync(h1, 0, (size_t)NN * 512 * sizeof(float), stream);
    layer_kernel<<<EE / 4, 256, 0, stream>>>(h0, h1, ei, ei + EE, rcnt, wt,
                                             bpb, ipb, opb, g1, b1, g2, b2, f1b, f2b);
    hipMemsetAsync(h0, 0, (size_t)NN * 512 * sizeof(float), stream);
    layer_kernel<<<EE / 4, 256, 0, stream>>>(h1, h0, ei, ei + EE, rcnt, wt + 28672,
                                             bpb + 64, ipb + 192, opb + 64,
                                             g1 + 64, b1 + 64, g2 + 64, b2 + 64, f1b + 64, f2b + 64);
    out_kernel<<<NN / 16, 256, 0, stream>>>(h0, ow, ob, (float*)d_out);
}

// Round 2
// 2283.386 us; speedup vs baseline: 1.2986x; 1.2986x over previous
//
#include <hip/hip_runtime.h>

#define NN 50000
#define EE 100000
#define LL 2

typedef __attribute__((ext_vector_type(8))) short short8;
typedef __attribute__((ext_vector_type(4))) float f32x4;

__device__ __forceinline__ short f2bf(float x) {
    unsigned u = __float_as_uint(x);
    unsigned r = (u + 0x7fffu + ((u >> 16) & 1u)) >> 16;
    return (short)(unsigned short)r;
}

// ---------------- small prep kernels ----------------

__global__ __launch_bounds__(256)
void count_kernel(const int* __restrict__ tgt, float* __restrict__ rcnt) {
    int e = blockIdx.x * 256 + threadIdx.x;
    if (e < EE) atomicAdd(&rcnt[tgt[e]], 1.0f);
}

__global__ __launch_bounds__(256)
void recip_kernel(float* __restrict__ rcnt) {
    int n = blockIdx.x * 256 + threadIdx.x;
    if (n < NN) rcnt[n] = 1.0f / fmaxf(rcnt[n], 1.0f);
}

__global__ __launch_bounds__(256)
void embed_kernel(const float* __restrict__ x, const float* __restrict__ nw,
                  const float* __restrict__ nb, float* __restrict__ h0) {
    int gid = blockIdx.x * 256 + threadIdx.x;
    if (gid >= NN * 512) return;
    int n = gid >> 9, j = gid & 511;
    h0[gid] = x[n * 8 + (j >> 6)] * nw[j] + nb[j];
}

// Build bf16 B-fragments for all weights.
// Frag f (1024 B): lane l, elem j holds W[nt*16 + (l&15)][ks*32 + (l>>4)*8 + j]
// Order: f 0..7 bproj | 8..31 ipw | 32..39 opw | 40..47 ff1 | 48..55 ff2.
__global__ __launch_bounds__(256)
void prep_frags(const float* __restrict__ bpw, const float* __restrict__ ipw,
                const float* __restrict__ opw, const float* __restrict__ f1w,
                const float* __restrict__ f2w, short* __restrict__ wtb) {
    int gid = blockIdx.x * 256 + threadIdx.x;
    if (gid >= LL * 28672) return;
    int l = gid / 28672, u = gid % 28672;
    int f = u >> 9;
    int el = u & 511;
    int ln = el >> 3, j = el & 7;
    int row16 = ln & 15, kg = ln >> 4;
    const float* W;
    int t;
    if (f < 8)       { W = bpw + l * 4096;  t = f; }
    else if (f < 32) { W = ipw + l * 12288; t = f - 8; }
    else if (f < 40) { W = opw + l * 4096;  t = f - 32; }
    else if (f < 48) { W = f1w + l * 4096;  t = f - 40; }
    else             { W = f2w + l * 4096;  t = f - 48; }
    int nt = t >> 1, ks = t & 1;
    int r = nt * 16 + row16, col = ks * 32 + kg * 8 + j;
    wtb[(size_t)l * 28672 + u] = f2bf(W[r * 64 + col]);
}

// ---------------- fused per-edge layer kernel (MFMA) ----------------

__device__ __forceinline__ void ln64(float x[4][4], const float* gv, const float* bv, int c) {
    float gg[4], bb[4];
#pragma unroll
    for (int nt = 0; nt < 4; nt++) { gg[nt] = gv[nt * 16 + c]; bb[nt] = bv[nt * 16 + c]; }
#pragma unroll
    for (int r = 0; r < 4; r++) {
        float s1 = x[0][r] + x[1][r] + x[2][r] + x[3][r];
        float s2 = x[0][r] * x[0][r];
#pragma unroll
        for (int nt = 1; nt < 4; nt++) s2 = fmaf(x[nt][r], x[nt][r], s2);
#pragma unroll
        for (int m = 1; m < 16; m <<= 1) { s1 += __shfl_xor(s1, m); s2 += __shfl_xor(s2, m); }
        float mean = s1 * 0.015625f;
        float var = fmaf(s2, 0.015625f, -mean * mean);
        float rs = rsqrtf(var + 1e-5f);
#pragma unroll
        for (int nt = 0; nt < 4; nt++) x[nt][r] = fmaf((x[nt][r] - mean) * rs, gg[nt], bb[nt]);
    }
}

__global__ __launch_bounds__(256)
void layer_kernel(const float* __restrict__ h_in, float* __restrict__ h_out,
                  const int* __restrict__ src, const int* __restrict__ tgt,
                  const float* __restrict__ rcnt, const short* __restrict__ wfr,
                  const float* __restrict__ bpb, const float* __restrict__ ipb,
                  const float* __restrict__ opb,
                  const float* __restrict__ g1v, const float* __restrict__ b1v,
                  const float* __restrict__ g2v, const float* __restrict__ b2v,
                  const float* __restrict__ f1b, const float* __restrict__ f2b)
{
    // LDS: [0,40960) weight frags (ipw 0..23, opw 24..31, ff1 32..39), then 4 waves x 2 bufs x 2048
    __shared__ __align__(16) char smem[57344];
    const int tid = threadIdx.x, wv = tid >> 6, lane = tid & 63;
    const int g = lane >> 4, c = lane & 15;
    const int swz = (c & 7) << 4;

    // copy frags 8..47 (global shorts [8*512, 48*512)) into LDS [0, 40960)
    {
        const int4* sw = (const int4*)(wfr + 8 * 512);
        int4* dw = (int4*)smem;
        for (int i = tid; i < 40960 / 16; i += 256) dw[i] = sw[i];
    }
    __syncthreads();

    char* buf0 = smem + 40960 + wv * 4096;
    char* buf1 = buf0 + 2048;
    const short8* gw = (const short8*)wfr;   // global frags (bproj f0..7, ff2 f48..55)
    const f32x4 zf = {};
    const short8 z8 = {};

#define LDA(B, ks)  (*(const short8*)&(B)[c * 128 + (((ks) * 64 + g * 16) ^ swz)])
#define LDH(B, h)   (*(const short8*)&(B)[c * 128 + (((h) * 32 + (g & 1) * 16) ^ swz)])
#define LFRAG(lf)   (*(const short8*)&smem[(lf) * 1024 + lane * 16])
#define MFMA(a, b, cc) __builtin_amdgcn_mfma_f32_16x16x32_bf16((a), (b), (cc), 0, 0, 0)

    for (int e = blockIdx.x * 4 + wv; e < EE; e += gridDim.x * 4) {
        const int sn = src[e], tn = tgt[e];
        const float* hs = h_in + (size_t)sn * 512;
        const float* ht = h_in + (size_t)tn * 512;

        // ---- S0: T0 tile [16][64] bf16 = [x_i ; x_j] (swizzled) ----
#pragma unroll
        for (int t = 0; t < 16; t++) {
            float v = (t < 8) ? ht[t * 64 + lane] : hs[(t - 8) * 64 + lane];
            *(short*)&buf0[t * 128 + ((lane * 2) ^ ((t & 7) << 4))] = f2bf(v);
        }

        // residual xc in C/D layout: rows 0..7 (lanes<32) = x_i from global fp32
        float xc[4][4];
        if (lane < 32) {
#pragma unroll
            for (int nt = 0; nt < 4; nt++)
#pragma unroll
                for (int r = 0; r < 4; r++)
                    xc[nt][r] = ht[(g * 4 + r) * 64 + nt * 16 + c];
        }

        // ---- S1: bproj (rows 8..15 = x_j @ Wb^T + bb) ----
        short8 a0 = LDA(buf0, 0), a1 = LDA(buf0, 1);
#pragma unroll
        for (int nt = 0; nt < 4; nt++) {
            f32x4 acc = zf;
            acc = MFMA(a0, gw[(nt * 2 + 0) * 64 + lane], acc);
            acc = MFMA(a1, gw[(nt * 2 + 1) * 64 + lane], acc);
            if (lane >= 32) {
                float bb = bpb[nt * 16 + c];
#pragma unroll
                for (int r = 0; r < 4; r++) {
                    float y = acc[r] + bb;
                    xc[nt][r] = y;
                    int row = g * 4 + r;
                    *(short*)&buf0[row * 128 + (((nt * 16 + c) * 2) ^ ((row & 7) << 4))] = f2bf(y);
                }
            }
        }

        // ---- S2: in_proj -> Q,K,V ----
        a0 = LDA(buf0, 0); a1 = LDA(buf0, 1);
        f32x4 qv[4], kv[4], vv[4];
#pragma unroll
        for (int nt = 0; nt < 4; nt++) {
            qv[nt] = MFMA(a1, LFRAG(nt * 2 + 1),        MFMA(a0, LFRAG(nt * 2 + 0),        zf));
            kv[nt] = MFMA(a1, LFRAG((nt + 4) * 2 + 1),  MFMA(a0, LFRAG((nt + 4) * 2 + 0),  zf));
            vv[nt] = MFMA(a1, LFRAG((nt + 8) * 2 + 1),  MFMA(a0, LFRAG((nt + 8) * 2 + 0),  zf));
        }
        // bias + write Q-tile (buf0, T0 dead) and K-tile (buf1); V stays in regs
#pragma unroll
        for (int nt = 0; nt < 4; nt++) {
            float bq = ipb[nt * 16 + c], bk = ipb[(nt + 4) * 16 + c], bv = ipb[(nt + 8) * 16 + c];
#pragma unroll
            for (int r = 0; r < 4; r++) {
                int row = g * 4 + r;
                int sw = (row & 7) << 4;
                int cb = (nt * 16 + c) * 2;
                *(short*)&buf0[row * 128 + (cb ^ sw)] = f2bf(qv[nt][r] + bq);
                *(short*)&buf1[row * 128 + (cb ^ sw)] = f2bf(kv[nt][r] + bk);
                vv[nt][r] += bv;
            }
        }

        // ---- S3: attention (4 heads), S^T = K @ Q^T, softmax over rows, O = P @ V ----
        float ov[4][4];
#pragma unroll
        for (int h = 0; h < 4; h++) {
            short8 kf = LDH(buf1, h);
            short8 qf = LDH(buf0, h);
            if (lane >= 32) kf = z8;      // zero-pad k>=16 (A side only)
            f32x4 st = MFMA(kf, qf, zf);
            float p[4];
#pragma unroll
            for (int r = 0; r < 4; r++) p[r] = st[r] * 0.25f;
            float m4 = fmaxf(fmaxf(p[0], p[1]), fmaxf(p[2], p[3]));
            m4 = fmaxf(m4, __shfl_xor(m4, 16));
            m4 = fmaxf(m4, __shfl_xor(m4, 32));
            float s4 = 0.f;
#pragma unroll
            for (int r = 0; r < 4; r++) { p[r] = __expf(p[r] - m4); s4 += p[r]; }
            s4 += __shfl_xor(s4, 16);
            s4 += __shfl_xor(s4, 32);
            float inv = 1.0f / s4;
#pragma unroll
            for (int r = 0; r < 4; r++) p[r] *= inv;
            // redistribute P (C/D of S^T) into A-frag layout; same perm feeds V B-frag
            short8 pa, vb;
#pragma unroll
            for (int j = 0; j < 8; j++) {
                int srcl = g * 32 + ((j >> 2) << 4) + c;
                pa[j] = f2bf(__shfl(p[j & 3], srcl));
                vb[j] = f2bf(__shfl(vv[h][j & 3], srcl));
            }
            if (lane >= 32) pa = z8;      // zero-pad k>=16
            f32x4 o = MFMA(pa, vb, zf);
#pragma unroll
            for (int r = 0; r < 4; r++) ov[h][r] = o[r];
        }
        // write O tile into buf1 (K dead)
#pragma unroll
        for (int h = 0; h < 4; h++)
#pragma unroll
            for (int r = 0; r < 4; r++) {
                int row = g * 4 + r;
                *(short*)&buf1[row * 128 + (((h * 16 + c) * 2) ^ ((row & 7) << 4))] = f2bf(ov[h][r]);
            }

        // ---- S4: out_proj + residual + LN1 ----
        a0 = LDA(buf1, 0); a1 = LDA(buf1, 1);
        float x1[4][4];
#pragma unroll
        for (int nt = 0; nt < 4; nt++) {
            f32x4 acc = MFMA(a1, LFRAG(24 + nt * 2 + 1), MFMA(a0, LFRAG(24 + nt * 2 + 0), zf));
            float bo = opb[nt * 16 + c];
#pragma unroll
            for (int r = 0; r < 4; r++) x1[nt][r] = acc[r] + bo + xc[nt][r];
        }
        ln64(x1, g1v, b1v, c);

        // ---- S5: FF ----
        // T1 (buf0) = x1
#pragma unroll
        for (int nt = 0; nt < 4; nt++)
#pragma unroll
            for (int r = 0; r < 4; r++) {
                int row = g * 4 + r;
                *(short*)&buf0[row * 128 + (((nt * 16 + c) * 2) ^ ((row & 7) << 4))] = f2bf(x1[nt][r]);
            }
        a0 = LDA(buf0, 0); a1 = LDA(buf0, 1);
#pragma unroll
        for (int nt = 0; nt < 4; nt++) {
            f32x4 acc = MFMA(a1, LFRAG(32 + nt * 2 + 1), MFMA(a0, LFRAG(32 + nt * 2 + 0), zf));
            float bf = f1b[nt * 16 + c];
#pragma unroll
            for (int r = 0; r < 4; r++) {
                float y = fmaxf(acc[r] + bf, 0.0f);
                int row = g * 4 + r;
                *(short*)&buf1[row * 128 + (((nt * 16 + c) * 2) ^ ((row & 7) << 4))] = f2bf(y);
            }
        }
        a0 = LDA(buf1, 0); a1 = LDA(buf1, 1);
        float x2[4][4];
#pragma unroll
        for (int nt = 0; nt < 4; nt++) {
            f32x4 acc = MFMA(a1, gw[(48 + nt * 2 + 1) * 64 + lane],
                        MFMA(a0, gw[(48 + nt * 2 + 0) * 64 + lane], zf));
            float bf = f2b[nt * 16 + c];
#pragma unroll
            for (int r = 0; r < 4; r++) x2[nt][r] = acc[r] + bf + x1[nt][r];
        }
        ln64(x2, g2v, b2v, c);

        // ---- S6: scatter rows 0..7 with mean scaling ----
        float rc = rcnt[tn];
        if (lane < 32) {
#pragma unroll
            for (int nt = 0; nt < 4; nt++)
#pragma unroll
                for (int r = 0; r < 4; r++)
                    atomicAdd(&h_out[(size_t)tn * 512 + (g * 4 + r) * 64 + nt * 16 + c],
                              x2[nt][r] * rc);
        }
    }
#undef LDA
#undef LDH
#undef LFRAG
#undef MFMA
}

// ---------------- final projection + softmax ----------------

__global__ __launch_bounds__(256)
void out_kernel(const float* __restrict__ h, const float* __restrict__ ow,
                const float* __restrict__ ob, float* __restrict__ out)
{
    __shared__ __align__(16) float hl[16 * 516];
    __shared__ __align__(16) float wl[16 * 68];
    __shared__ float bl[16];
    const int tid = threadIdx.x;
    const int n0 = blockIdx.x * 16;
#pragma unroll
    for (int i = 0; i < 4; i++) {
        int idx = i * 256 + tid;
        wl[(idx >> 6) * 68 + (idx & 63)] = ow[idx];
    }
    if (tid < 16) bl[tid] = ob[tid];
#pragma unroll
    for (int i = 0; i < 32; i++) {
        int idx = i * 256 + tid; int nl = idx >> 9, j = idx & 511;
        hl[nl * 516 + j] = h[(size_t)(n0 + nl) * 512 + j];
    }
    __syncthreads();
    const int nl = tid >> 4, o = tid & 15;
    float acc = 0;
#pragma unroll 4
    for (int d4 = 0; d4 < 16; d4++) {
        float4 wv = *(const float4*)&wl[o * 68 + d4 * 4];
#pragma unroll
        for (int cc = 0; cc < 8; cc++) {
            float4 hv = *(const float4*)&hl[nl * 516 + cc * 64 + d4 * 4];
            acc += hv.x * wv.x + hv.y * wv.y + hv.z * wv.z + hv.w * wv.w;
        }
    }
    float z = acc + 8.0f * bl[o];
    float mxv = z;
#pragma unroll
    for (int m = 1; m < 16; m <<= 1) mxv = fmaxf(mxv, __shfl_xor(mxv, m));
    float ez = __expf(z - mxv);
    float sm = ez;
#pragma unroll
    for (int m = 1; m < 16; m <<= 1) sm += __shfl_xor(sm, m);
    out[(size_t)(n0 + nl) * 16 + o] = ez / sm;
}

// ---------------- launch ----------------

extern "C" void kernel_launch(void* const* d_in, const int* in_sizes, int n_in,
                              void* d_out, int out_size, void* d_ws, size_t ws_size,
                              hipStream_t stream)
{
    const float* x   = (const float*)d_in[0];
    const int*   ei  = (const int*)d_in[1];
    const float* nw  = (const float*)d_in[2];
    const float* nb  = (const float*)d_in[3];
    const float* bpw = (const float*)d_in[4];
    const float* bpb = (const float*)d_in[5];
    const float* ipw = (const float*)d_in[6];
    const float* ipb = (const float*)d_in[7];
    const float* opw = (const float*)d_in[8];
    const float* opb = (const float*)d_in[9];
    const float* g1  = (const float*)d_in[10];
    const float* b1  = (const float*)d_in[11];
    const float* g2  = (const float*)d_in[12];
    const float* b2  = (const float*)d_in[13];
    const float* f1w = (const float*)d_in[14];
    const float* f1b = (const float*)d_in[15];
    const float* f2w = (const float*)d_in[16];
    const float* f2b = (const float*)d_in[17];
    const float* ow  = (const float*)d_in[18];
    const float* ob  = (const float*)d_in[19];

    float* ws   = (float*)d_ws;
    float* h0   = ws;
    float* h1   = h0 + (size_t)NN * 512;
    float* rcnt = h1 + (size_t)NN * 512;
    short* wtb  = (short*)(rcnt + NN);   // 2*28672 bf16 frag elems (16B-aligned offset)

    hipMemsetAsync(rcnt, 0, NN * sizeof(float), stream);
    count_kernel<<<(EE + 255) / 256, 256, 0, stream>>>(ei + EE, rcnt);
    recip_kernel<<<(NN + 255) / 256, 256, 0, stream>>>(rcnt);
    prep_frags<<<(LL * 28672 + 255) / 256, 256, 0, stream>>>(bpw, ipw, opw, f1w, f2w, wtb);
    embed_kernel<<<(NN * 512) / 256, 256, 0, stream>>>(x, nw, nb, h0);

    hipMemsetAsync(h1, 0, (size_t)NN * 512 * sizeof(float), stream);
    layer_kernel<<<2048, 256, 0, stream>>>(h0, h1, ei, ei + EE, rcnt, wtb,
                                           bpb, ipb, opb, g1, b1, g2, b2, f1b, f2b);
    hipMemsetAsync(h0, 0, (size_t)NN * 512 * sizeof(float), stream);
    layer_kernel<<<2048, 256, 0, stream>>>(h1, h0, ei, ei + EE, rcnt, wtb + 28672,
                                           bpb + 64, ipb + 192, opb + 64,
                                           g1 + 64, b1 + 64, g2 + 64, b2 + 64, f1b + 64, f2b + 64);
    out_kernel<<<NN / 16, 256, 0, stream>>>(h0, ow, ob, (float*)d_out);
}